// Round 12
// baseline (153.317 us; speedup 1.0000x reference)
//
#include <hip/hip_runtime.h>

// Lovász-Softmax (B=1, C=3) — degenerate closed form (verified R1–R11, absmax=0):
//   loss = mean over present classes c of weight[c] * mean_{lab==c}(-log(softmax_c + 1e-8))
// R12: front-count test WITHOUT occupancy confound. BLK 256→512, 256 blocks
// (exact fit P4 = 256*6144), 1 block/CU — same 8 waves/CU as R11 but 96 KB
// contiguous per stream per block, halving concurrent DRAM stream fronts
// (2560→1280). Trend so far: 12KB=36µs, 24KB=32.5µs, 48KB=31.5µs.
// nt loads bypass L1 set-aliasing (5 streams ≡0 mod 32KB apart);
// err = log(e^za+e^zb+e^zc) - z_lab (R9-verified, absmax 0).

#define EPS 1e-8f
#define BLK 512
#define GPT 12         // float4 groups per thread
#define GPB (GPT*BLK)  // groups per block = 6144
#define NWAVE (BLK/64) // 8 waves per block

typedef float fx4 __attribute__((ext_vector_type(4)));
typedef int   ix4 __attribute__((ext_vector_type(4)));

__device__ __forceinline__ void px_acc(float za, float zb, float zc, int la, int lb,
                                       float& s0, float& s1, float& s2,
                                       float& n0, float& n1, float& n2)
{
    float ea = __expf(za);
    float eb = __expf(zb);
    float ec = __expf(zc);
    float d  = ea + eb + ec;
    float zl = (la != 0) ? zb : ((lb != 0) ? zc : za);
    float err = __logf(d) - zl;          // == -log(softmax_lab), eps dropped
    float f1 = (la != 0) ? 1.f : 0.f;
    float f2 = (lb != 0) ? 1.f : 0.f;
    float f0 = 1.f - f1 - f2;
    s0 += f0 * err;  s1 += f1 * err;  s2 += f2 * err;
    n0 += f0;        n1 += f1;        n2 += f2;
}

__global__ __launch_bounds__(BLK) void lovasz_reduce_kernel(
    const float* __restrict__ probas,   // [3, P] channel-major
    const int*   __restrict__ labels,   // [3, P] one-hot int32
    float* __restrict__ partial,        // ws: [6][nblocks] transposed partials
    int P4, int P, int nfull, int nblocks)
{
    const fx4* z0 = (const fx4*)(probas);
    const fx4* z1 = (const fx4*)(probas + (size_t)P);
    const fx4* z2 = (const fx4*)(probas + 2 * (size_t)P);
    const ix4* l1 = (const ix4*)(labels + (size_t)P);
    const ix4* l2 = (const ix4*)(labels + 2 * (size_t)P);

    float s0 = 0.f, s1 = 0.f, s2 = 0.f;
    float n0 = 0.f, n1 = 0.f, n2 = 0.f;

    const int base = blockIdx.x * GPB + threadIdx.x;

    if (blockIdx.x < nfull) {
        #pragma unroll
        for (int j = 0; j < GPT; ++j) {
            int i = base + j * BLK;
            fx4 a = __builtin_nontemporal_load(&z0[i]);
            fx4 b = __builtin_nontemporal_load(&z1[i]);
            fx4 c = __builtin_nontemporal_load(&z2[i]);
            ix4 u = __builtin_nontemporal_load(&l1[i]);
            ix4 v = __builtin_nontemporal_load(&l2[i]);
            px_acc(a.x, b.x, c.x, u.x, v.x, s0, s1, s2, n0, n1, n2);
            px_acc(a.y, b.y, c.y, u.y, v.y, s0, s1, s2, n0, n1, n2);
            px_acc(a.z, b.z, c.z, u.z, v.z, s0, s1, s2, n0, n1, n2);
            px_acc(a.w, b.w, c.w, u.w, v.w, s0, s1, s2, n0, n1, n2);
        }
    } else {
        #pragma unroll
        for (int j = 0; j < GPT; ++j) {
            int i = base + j * BLK;
            if (i < P4) {
                fx4 a = __builtin_nontemporal_load(&z0[i]);
                fx4 b = __builtin_nontemporal_load(&z1[i]);
                fx4 c = __builtin_nontemporal_load(&z2[i]);
                ix4 u = __builtin_nontemporal_load(&l1[i]);
                ix4 v = __builtin_nontemporal_load(&l2[i]);
                px_acc(a.x, b.x, c.x, u.x, v.x, s0, s1, s2, n0, n1, n2);
                px_acc(a.y, b.y, c.y, u.y, v.y, s0, s1, s2, n0, n1, n2);
                px_acc(a.z, b.z, c.z, u.z, v.z, s0, s1, s2, n0, n1, n2);
                px_acc(a.w, b.w, c.w, u.w, v.w, s0, s1, s2, n0, n1, n2);
            }
        }
    }

    // wave (64-lane) shuffle reduction
    #pragma unroll
    for (int off = 32; off > 0; off >>= 1) {
        s0 += __shfl_down(s0, off);
        s1 += __shfl_down(s1, off);
        s2 += __shfl_down(s2, off);
        n0 += __shfl_down(n0, off);
        n1 += __shfl_down(n1, off);
        n2 += __shfl_down(n2, off);
    }

    __shared__ float red[6][NWAVE];
    int wave = threadIdx.x >> 6;
    int lane = threadIdx.x & 63;
    if (lane == 0) {
        red[0][wave] = s0; red[1][wave] = s1; red[2][wave] = s2;
        red[3][wave] = n0; red[4][wave] = n1; red[5][wave] = n2;
    }
    __syncthreads();
    if (threadIdx.x < 6) {
        int k = threadIdx.x;
        float v = 0.f;
        #pragma unroll
        for (int w = 0; w < NWAVE; ++w) v += red[k][w];
        partial[(size_t)k * nblocks + blockIdx.x] = v;
    }
}

__global__ __launch_bounds__(256) void lovasz_finalize_kernel(
    const float* __restrict__ partial, int nblocks,
    const float* __restrict__ probas, const int* __restrict__ labels,
    const float* __restrict__ weight, float* __restrict__ out,
    int P4, int P)
{
    float acc[6] = {0.f, 0.f, 0.f, 0.f, 0.f, 0.f};
    for (int b = threadIdx.x; b < nblocks; b += 256) {
        #pragma unroll
        for (int k = 0; k < 6; ++k)
            acc[k] += partial[(size_t)k * nblocks + b];
    }

    #pragma unroll
    for (int k = 0; k < 6; ++k)
        #pragma unroll
        for (int off = 32; off > 0; off >>= 1)
            acc[k] += __shfl_down(acc[k], off);

    __shared__ float red[6][4];
    int wave = threadIdx.x >> 6;
    int lane = threadIdx.x & 63;
    if (lane == 0) {
        #pragma unroll
        for (int k = 0; k < 6; ++k) red[k][wave] = acc[k];
    }
    __syncthreads();
    if (threadIdx.x == 0) {
        float s[6];
        #pragma unroll
        for (int k = 0; k < 6; ++k)
            s[k] = red[k][0] + red[k][1] + red[k][2] + red[k][3];
        // scalar tail (P % 4 != 0; empty for this shape)
        for (int i = 4 * P4; i < P; ++i) {
            px_acc(probas[i], probas[(size_t)P + i], probas[2 * (size_t)P + i],
                   labels[(size_t)P + i], labels[2 * (size_t)P + i],
                   s[0], s[1], s[2], s[3], s[4], s[5]);
        }
        float total = 0.f, cnt = 0.f;
        #pragma unroll
        for (int c = 0; c < 3; ++c) {
            if (s[3 + c] > 0.f) {
                total += weight[c] * s[c] / s[3 + c];
                cnt += 1.f;
            }
        }
        out[0] = (cnt > 0.f) ? total / cnt : 0.f;
    }
}

extern "C" void kernel_launch(void* const* d_in, const int* in_sizes, int n_in,
                              void* d_out, int out_size, void* d_ws, size_t ws_size,
                              hipStream_t stream) {
    const float* probas = (const float*)d_in[0];
    const float* weight = (const float*)d_in[1];
    const int*   labels = (const int*)d_in[2];
    float* partial = (float*)d_ws;

    int total = in_sizes[0];        // B*C*D*H*W with B=1, C=3
    int P  = total / 3;             // pixels = 6,291,456
    int P4 = P / 4;                 // 1,572,864 float4 groups
    int nfull = P4 / GPB;           // 256 fully-covered blocks (1/CU)
    int rem = P4 - nfull * GPB;
    int nblocks = nfull + (rem ? 1 : 0);

    lovasz_reduce_kernel<<<nblocks, BLK, 0, stream>>>(probas, labels, partial,
                                                      P4, P, nfull, nblocks);
    lovasz_finalize_kernel<<<1, 256, 0, stream>>>(partial, nblocks, probas,
                                                  labels, weight, (float*)d_out,
                                                  P4, P);
}